// Round 15
// baseline (186.882 us; speedup 1.0000x reference)
//
#include <hip/hip_runtime.h>

// GraphAttentionLayer: B=1, N=4096, F=256, H=8, U=64
//
// e_src cancels in softmax over j =>
//   out[i, u*8+h] = relu( (A @ (w*h))[i, h*64+u] / (A @ w)[i, h] ),  w = exp(e_dst)
// => ONE dense GEMM  C = A(4096x4096) x G(4096x544), G = [w*h (512) | w (8) | 0 (24)]
//
// R18: eliminate k_out ALGEBRAICALLY (R17 lesson: cross-XCD producer->consumer
// must cross a kernel boundary; intra-kernel fences/sync don't invalidate
// reader L2 -> 0.27 absmax). Z=1: each k_gemm block accumulates FULL K=4096,
// so after the in-block den reduce it divides in-register and stores straight
// to out. No P, no k_out, 2 kernels, 1 boundary. Decisive test of the ~50us
// phantom (k_out+boundaries vs inside-k_hg).
//  k_hg: R14-frozen (8 waves, split-bf16 3-pass MFMA).
//  k_gemm: BM=32, N-split (nh), wave owns n-tile nh*8+w, 16 chunks of BK=256,
//  4-deep B-loads (R7/R10-proven shape), den round-robin (ALL blocks now) +
//  LDS reduce + in-register relu(num/den) -> out. Grid 256 = 1 blk/CU.
//
// Gtp layout (HW-verified R4): tile (tk=k>>4, nt=n>>5), id=tk*17+nt, 1024 B:
//   u16[ id*512 + ((n&31) + 32*((k&15)>>3))*8 + (k&7) ]
// A/B MFMA frag (HW-verified R11): data[lane*8+i] = M[row=lane&31][k=(lane>>5)*8+i]
//
// ws: Gtp @0 (4,456,448 B). (P eliminated.)

typedef unsigned short u16;
typedef unsigned int   u32;
typedef __attribute__((ext_vector_type(8)))  short  short8;    // 8 bf16 (4 VGPR)
typedef __attribute__((ext_vector_type(16))) float  floatx16;  // 32x32 MFMA acc
typedef __attribute__((ext_vector_type(8)))  unsigned short u16x8;
typedef __attribute__((ext_vector_type(4)))  unsigned short u16x4;

__device__ __forceinline__ u16 f2bf(float x) {
  u32 u = __float_as_uint(x);
  u += 0x7fffu + ((u >> 16) & 1u);   // RNE
  return (u16)(u >> 16);
}
__device__ __forceinline__ float bf2f(u16 h) {
  return __uint_as_float((u32)h << 16);
}
// split fp32[8] -> hi/lo bf16 short8 (hi RNE; lo = RNE(x - hi), rel err ~2^-17)
__device__ __forceinline__ void split8(const float* v, short8& hi, short8& lo) {
#pragma unroll
  for (int i = 0; i < 8; ++i) {
    u16 h = f2bf(v[i]);
    hi[i] = (short)h;
    lo[i] = (short)f2bf(v[i] - bf2f(h));
  }
}

// ---------------------------------------------------------------------------
// Kernel 1: h = X@W via split-bf16 3-pass MFMA, e_dst -> w = exp, write Gtp.
// (R14-frozen: 512 thr = 8 waves = 4 n-tiles x 2 K-halves; ks=1 partials via
// LDS; no LDS staging in K loop. Grid (128,4) = 512 blocks = 4 waves/SIMD.)
// ---------------------------------------------------------------------------
__global__ __launch_bounds__(512, 4) void k_hg(const float* __restrict__ X,
                                               const float* __restrict__ W,
                                               const float* __restrict__ av,
                                               u16* __restrict__ Gtp) {
  __shared__ float hbuf[4][64][17];   // partial-h exchange, pad 17 (17.4 KB)
  __shared__ float eL[64];            // [j_local*2 + head_local]
  __shared__ float w8L[64];
  const int t    = threadIdx.x;
  const int bx   = blockIdx.x;         // m-tile (32 j)
  const int y    = blockIdx.y;         // heads 2y, 2y+1
  const int j0   = bx * 32;
  const int wn   = t >> 6, lane = t & 63;
  const int ml   = lane & 31, kh = lane >> 5;
  const int wq   = wn & 3;             // n-tile slot
  const int ks   = wn >> 2;            // K-half
  const int ct   = y * 4 + wq;
  const int c    = ct * 32 + ml;       // global col (0..511)
  const int hl   = wq >> 1;            // head_local 0/1

  if (t < 64) eL[t] = 0.f;
  __syncthreads();

  floatx16 a0, a1;
#pragma unroll
  for (int r = 0; r < 16; ++r) { a0[r] = 0.f; a1[r] = 0.f; }

  const float* xrow = X + (size_t)(j0 + ml) * 256 + kh * 8;   // this lane's A row
  const float* wcol = W + (size_t)(kh * 8) * 512 + c;          // this lane's B col

#pragma unroll
  for (int kp = 0; kp < 4; ++kp) {     // kt = ks*8 + 2kp, +1
    const int kb0 = (ks * 8 + 2 * kp) * 16, kb1 = kb0 + 16;
    float xv0[8], xv1[8];
    {
      float4 u0 = *(const float4*)(xrow + kb0);
      float4 u1 = *(const float4*)(xrow + kb0 + 4);
      float4 u2 = *(const float4*)(xrow + kb1);
      float4 u3 = *(const float4*)(xrow + kb1 + 4);
      xv0[0]=u0.x; xv0[1]=u0.y; xv0[2]=u0.z; xv0[3]=u0.w;
      xv0[4]=u1.x; xv0[5]=u1.y; xv0[6]=u1.z; xv0[7]=u1.w;
      xv1[0]=u2.x; xv1[1]=u2.y; xv1[2]=u2.z; xv1[3]=u2.w;
      xv1[4]=u3.x; xv1[5]=u3.y; xv1[6]=u3.z; xv1[7]=u3.w;
    }
    float wv0[8], wv1[8];
#pragma unroll
    for (int i = 0; i < 8; ++i) {
      wv0[i] = wcol[(size_t)(kb0 + i) * 512];
      wv1[i] = wcol[(size_t)(kb1 + i) * 512];
    }
    short8 xh0, xl0, xh1, xl1, wh0, wl0, wh1, wl1;
    split8(xv0, xh0, xl0); split8(xv1, xh1, xl1);
    split8(wv0, wh0, wl0); split8(wv1, wh1, wl1);
    a0 = __builtin_amdgcn_mfma_f32_32x32x16_bf16(xh0, wh0, a0, 0, 0, 0);
    a1 = __builtin_amdgcn_mfma_f32_32x32x16_bf16(xh1, wh1, a1, 0, 0, 0);
    a0 = __builtin_amdgcn_mfma_f32_32x32x16_bf16(xh0, wl0, a0, 0, 0, 0);
    a1 = __builtin_amdgcn_mfma_f32_32x32x16_bf16(xh1, wl1, a1, 0, 0, 0);
    a0 = __builtin_amdgcn_mfma_f32_32x32x16_bf16(xl0, wh0, a0, 0, 0, 0);
    a1 = __builtin_amdgcn_mfma_f32_32x32x16_bf16(xl1, wh1, a1, 0, 0, 0);
  }
  floatx16 hacc;
#pragma unroll
  for (int r = 0; r < 16; ++r) hacc[r] = a0[r] + a1[r];

  // combine K-halves: ks=1 deposits, ks=0 adds
  if (ks == 1) {
#pragma unroll
    for (int r = 0; r < 16; ++r) hbuf[wq][lane][r] = hacc[r];
  }
  __syncthreads();
  if (ks == 0) {
#pragma unroll
    for (int r = 0; r < 16; ++r) hacc[r] += hbuf[wq][lane][r];

    const float ad = av[64 + (c & 63)];
    float p[16];
#pragma unroll
    for (int r = 0; r < 16; ++r) p[r] = hacc[r] * ad;
#pragma unroll
    for (int m = 1; m <= 16; m <<= 1)
#pragma unroll
      for (int r = 0; r < 16; ++r) p[r] += __shfl_xor(p[r], m);
    if (ml == 0) {
#pragma unroll
      for (int r = 0; r < 16; ++r) {
        int jl = (r & 3) + 8 * (r >> 2) + 4 * kh;
        atomicAdd(&eL[jl * 2 + hl], p[r]);
      }
    }
  }
  __syncthreads();
  if (t < 64) {
    float e = fminf(30.f, fmaxf(-30.f, eL[t]));
    w8L[t] = __expf(e);
  }
  __syncthreads();

  if (ks == 0) {
#pragma unroll
    for (int r = 0; r < 16; ++r) {
      int jl = (r & 3) + 8 * (r >> 2) + 4 * kh;
      int j  = j0 + jl;
      float g = hacc[r] * w8L[jl * 2 + hl];
      Gtp[(size_t)((j >> 4) * 17 + ct) * 512 + ((c & 31) + 32 * ((j & 15) >> 3)) * 8 + (j & 7)] =
          f2bf(g);
    }
  }
  if (t < 64) {
    int jj = t >> 1, lh2 = t & 1, h = 2 * y + lh2, j = j0 + jj;
    Gtp[(size_t)((j >> 4) * 17 + 16) * 512 + (h + 32 * ((jj & 15) >> 3)) * 8 + (jj & 7)] =
        f2bf(w8L[jj * 2 + lh2]);
  }
  if (y == 3 && t < 96) {
    int tk2 = t / 48, r = t - tk2 * 48;
    int slot = (r < 24) ? (8 + r) : (16 + r);
    u16x8 z = {0, 0, 0, 0, 0, 0, 0, 0};
    *(u16x8*)(Gtp + (size_t)(((j0 >> 4) + tk2) * 17 + 16) * 512 + slot * 8) = z;
  }
}

// ---------------------------------------------------------------------------
// Kernel 2: out = relu( (A x G^T)[num] / (A x G^T)[den] ) — FULL K per block.
// Block: 512 thr = 8 waves, BM=32, N-split (nh): wave owns n-tile nh*8+w.
// 16 chunks of BK=256; per ds-iter 4 indep B-loads + 4 A ds_reads + 4 MFMA
// (R7/R10-proven shape). Den tile: k-tiles {2w,2w+1} per chunk round-robin
// (ALL blocks), LDS-reduced at the end -> in-register relu(num/den) -> direct
// out stores. No P, no atomics, no fences. Grid 256 = 1 blk/CU.
// ---------------------------------------------------------------------------
__global__ __launch_bounds__(512, 2) void k_gemm(const float* __restrict__ A,
                                                 const u16* __restrict__ Gtp,
                                                 float* __restrict__ out) {
  __shared__ __align__(16) u16 As[2][32 * 256];  // 2 x 16 KB
  const int t    = threadIdx.x;
  const int bid  = blockIdx.x;
  const int nh   = bid & 1;                      // n-half
  const int strip = bid >> 1;                    // 0..127
  const int i0   = strip * 32;
  const int w    = t >> 6, lane = t & 63;
  const int ml   = lane & 31, kh = lane >> 5;
  const int nt   = nh * 8 + w;                   // this wave's n-tile

  floatx16 c0, dn;
#pragma unroll
  for (int r = 0; r < 16; ++r) { c0[r] = 0.f; dn[r] = 0.f; }

  // A staging: thread -> row ar (0..31), q-th float4 at k = (t&15)*4 + q*64
  const int ar  = t >> 4;
  const int af  = (t & 15) * 4;
  const float* pa = A + (size_t)(i0 + ar) * 4096 + af;
  const int sbase = ar * 256 + (t & 1) * 4;   // + swizzled granule*8
  const int scb   = (t & 15) >> 1;            // granule = q*8 + scb
  const int arx   = ar & 7;

  // A-frag reads: row m = ml, granule g -> physical g^(ml&7); k-tile j <-> granule 2j+kh
  const int arow = ml * 256;
  const int mx   = ml & 7;

  float4 areg[4];
#pragma unroll
  for (int q = 0; q < 4; ++q) areg[q] = *(const float4*)(pa + q * 64);
#pragma unroll
  for (int q = 0; q < 4; ++q) {
    u16x4 v = {f2bf(areg[q].x), f2bf(areg[q].y), f2bf(areg[q].z), f2bf(areg[q].w)};
    *(u16x4*)(&As[0][sbase + ((q * 8 + scb) ^ arx) * 8]) = v;
  }
  __syncthreads();

  for (int cc = 0; cc < 16; ++cc) {
    const int cb = cc & 1;
    if (cc < 15) {                   // prefetch next chunk early (hidden by compute)
#pragma unroll
      for (int q = 0; q < 4; ++q)
        areg[q] = *(const float4*)(pa + (cc + 1) * 256 + q * 64);
    }
    const int ktb = cc * 16;
#pragma unroll 2
    for (int ds = 0; ds < 4; ++ds) {
      short8 b0 = *(const short8*)(Gtp + (size_t)((ktb + ds * 4 + 0) * 17 + nt) * 512 + lane * 8);
      short8 b1 = *(const short8*)(Gtp + (size_t)((ktb + ds * 4 + 1) * 17 + nt) * 512 + lane * 8);
      short8 b2 = *(const short8*)(Gtp + (size_t)((ktb + ds * 4 + 2) * 17 + nt) * 512 + lane * 8);
      short8 b3 = *(const short8*)(Gtp + (size_t)((ktb + ds * 4 + 3) * 17 + nt) * 512 + lane * 8);
      short8 a0 = *(const short8*)(&As[cb][arow + ((ds * 8 + 0 + kh) ^ mx) * 8]);
      short8 a1 = *(const short8*)(&As[cb][arow + ((ds * 8 + 2 + kh) ^ mx) * 8]);
      short8 a2 = *(const short8*)(&As[cb][arow + ((ds * 8 + 4 + kh) ^ mx) * 8]);
      short8 a3 = *(const short8*)(&As[cb][arow + ((ds * 8 + 6 + kh) ^ mx) * 8]);
      c0 = __builtin_amdgcn_mfma_f32_32x32x16_bf16(a0, b0, c0, 0, 0, 0);
      c0 = __builtin_amdgcn_mfma_f32_32x32x16_bf16(a1, b1, c0, 0, 0, 0);
      c0 = __builtin_amdgcn_mfma_f32_32x32x16_bf16(a2, b2, c0, 0, 0, 0);
      c0 = __builtin_amdgcn_mfma_f32_32x32x16_bf16(a3, b3, c0, 0, 0, 0);
    }
    // den tile 16: wave covers k-tiles {2w, 2w+1} of this chunk (all blocks)
    {
      short8 e0 = *(const short8*)(Gtp + (size_t)((ktb + w * 2) * 17 + 16) * 512 + lane * 8);
      short8 e1 = *(const short8*)(Gtp + (size_t)((ktb + w * 2 + 1) * 17 + 16) * 512 + lane * 8);
      short8 a0 = *(const short8*)(&As[cb][arow + ((w * 4 + kh) ^ mx) * 8]);
      short8 a1 = *(const short8*)(&As[cb][arow + ((w * 4 + 2 + kh) ^ mx) * 8]);
      dn = __builtin_amdgcn_mfma_f32_32x32x16_bf16(a0, e0, dn, 0, 0, 0);
      dn = __builtin_amdgcn_mfma_f32_32x32x16_bf16(a1, e1, dn, 0, 0, 0);
    }
    if (cc < 15) {
      __syncthreads();               // readers of other buffer done
#pragma unroll
      for (int q = 0; q < 4; ++q) {
        u16x4 v = {f2bf(areg[q].x), f2bf(areg[q].y), f2bf(areg[q].z), f2bf(areg[q].w)};
        *(u16x4*)(&As[cb ^ 1][sbase + ((q * 8 + scb) ^ arx) * 8]) = v;
      }
      __syncthreads();               // writes visible
    }
  }

  // ---- den reduce across 8 waves (LDS), then in-register division ----
  // As[0] free: last read in chunk cc==14 (cb=0); cc==15 reads As[1] only,
  // and the cc==14 barrier pair means no wave is still in cc<=14.
  float* dred = (float*)&As[0][0];   // 8 waves x 32 rows x 8 heads = 8 KB
  float* dsum = (float*)&As[0][0] + 2048;  // 32 rows x 8 heads = 1 KB
  if (ml < 8) {
#pragma unroll
    for (int r = 0; r < 16; ++r) {
      int row32 = 4 * kh + (r & 3) + 8 * (r >> 2);
      dred[(w * 32 + row32) * 8 + ml] = dn[r];
    }
  }
  __syncthreads();
  if (t < 256) {
    int row = t >> 3, hd = t & 7;    // 32 rows x 8 heads
    float s = 0.f;
#pragma unroll
    for (int ww = 0; ww < 8; ++ww) s += dred[(ww * 32 + row) * 8 + hd];
    dsum[row * 8 + hd] = s;
  }
  __syncthreads();

  // out[row, u*8+hd] = relu(c0 / den), n = nt*32+ml -> hd = nt>>1,
  // u = (nt&1)*32 + ml
  {
    const int hd   = nt >> 1;
    const int ucol = ((nt & 1) * 32 + ml) * 8 + hd;
#pragma unroll
    for (int r = 0; r < 16; ++r) {
      int row32 = 4 * kh + (r & 3) + 8 * (r >> 2);
      float den = dsum[row32 * 8 + hd];
      float o = fmaxf(c0[r] / den, 0.f);
      out[(size_t)(i0 + row32) * 512 + ucol] = o;
    }
  }
}

extern "C" void kernel_launch(void* const* d_in, const int* in_sizes, int n_in,
                              void* d_out, int out_size, void* d_ws, size_t ws_size,
                              hipStream_t stream) {
  const float* X  = (const float*)d_in[0];
  const float* A  = (const float*)d_in[1];
  const float* W  = (const float*)d_in[2];
  const float* av = (const float*)d_in[3];
  float* out = (float*)d_out;
  char*  ws  = (char*)d_ws;

  u16* Gtp = (u16*)ws;                      // 256*17 tiles * 1024 B

  k_hg<<<dim3(128, 4), 512, 0, stream>>>(X, W, av, Gtp);
  k_gemm<<<256, 512, 0, stream>>>(A, Gtp, out);
}

// Round 17
// 173.781 us; speedup vs baseline: 1.0754x; 1.0754x over previous
//
#include <hip/hip_runtime.h>

// GraphAttentionLayer: B=1, N=4096, F=256, H=8, U=64
//
// e_src cancels in softmax over j =>
//   out[i, u*8+h] = relu( (A @ (w*h))[i, h*64+u] / (A @ w)[i, h] ),  w = exp(e_dst)
// => ONE dense GEMM  C = A(4096x4096) x G(4096x544), G = [w*h (512) | w (8) | 0 (24)]
//
// R19 (2nd submit; round 16 was a container/infra failure — source audited
// clean: bounds, uniform barriers, LDS/VGPR budgets verified):
// R18's algebraic k_out-fusion at R10's TLP. R18 proved perf scales
// linearly with wave count (256 blocks = 92us, exactly 2x R10's 44 at half
// the waves); restore 512 blocks while keeping full-K-per-block:
//  k_gemm: grid 512 = 128 strips x 4 n-quarters; block = 32 rows x 4 n-tiles,
//  8 waves = (wq n-tile) x (ks K-half). Per wave: 1 n-tile x 128 k-tiles,
//  4 indep B-loads + 4 A ds_reads + 4 MFMA per ds-iter (R10's exact proven
//  shape). A staged 512-col chunks (2x32KB dbuf, R15-verified swizzle).
//  End: num combined across ks in LDS, den round-robin (all blocks, ksub
//  {4wq..4wq+3}) reduced across waves -> relu(num/den) -> direct out.
//  No P, no k_out, 1 boundary. k_hg: R14-frozen.
//
// Gtp layout (HW-verified R4): tile (tk=k>>4, nt=n>>5), id=tk*17+nt, 1024 B:
//   u16[ id*512 + ((n&31) + 32*((k&15)>>3))*8 + (k&7) ]
// A/B MFMA frag (HW-verified R11): data[lane*8+i] = M[row=lane&31][k=(lane>>5)*8+i]
//
// ws: Gtp @0 (4,456,448 B).

typedef unsigned short u16;
typedef unsigned int   u32;
typedef __attribute__((ext_vector_type(8)))  short  short8;    // 8 bf16 (4 VGPR)
typedef __attribute__((ext_vector_type(16))) float  floatx16;  // 32x32 MFMA acc
typedef __attribute__((ext_vector_type(8)))  unsigned short u16x8;
typedef __attribute__((ext_vector_type(4)))  unsigned short u16x4;

__device__ __forceinline__ u16 f2bf(float x) {
  u32 u = __float_as_uint(x);
  u += 0x7fffu + ((u >> 16) & 1u);   // RNE
  return (u16)(u >> 16);
}
__device__ __forceinline__ float bf2f(u16 h) {
  return __uint_as_float((u32)h << 16);
}
// split fp32[8] -> hi/lo bf16 short8 (hi RNE; lo = RNE(x - hi), rel err ~2^-17)
__device__ __forceinline__ void split8(const float* v, short8& hi, short8& lo) {
#pragma unroll
  for (int i = 0; i < 8; ++i) {
    u16 h = f2bf(v[i]);
    hi[i] = (short)h;
    lo[i] = (short)f2bf(v[i] - bf2f(h));
  }
}

// ---------------------------------------------------------------------------
// Kernel 1: h = X@W via split-bf16 3-pass MFMA, e_dst -> w = exp, write Gtp.
// (R14-frozen: 512 thr = 8 waves = 4 n-tiles x 2 K-halves; ks=1 partials via
// LDS; no LDS staging in K loop. Grid (128,4) = 512 blocks = 4 waves/SIMD.)
// ---------------------------------------------------------------------------
__global__ __launch_bounds__(512, 4) void k_hg(const float* __restrict__ X,
                                               const float* __restrict__ W,
                                               const float* __restrict__ av,
                                               u16* __restrict__ Gtp) {
  __shared__ float hbuf[4][64][17];   // partial-h exchange, pad 17 (17.4 KB)
  __shared__ float eL[64];            // [j_local*2 + head_local]
  __shared__ float w8L[64];
  const int t    = threadIdx.x;
  const int bx   = blockIdx.x;         // m-tile (32 j)
  const int y    = blockIdx.y;         // heads 2y, 2y+1
  const int j0   = bx * 32;
  const int wn   = t >> 6, lane = t & 63;
  const int ml   = lane & 31, kh = lane >> 5;
  const int wq   = wn & 3;             // n-tile slot
  const int ks   = wn >> 2;            // K-half
  const int ct   = y * 4 + wq;
  const int c    = ct * 32 + ml;       // global col (0..511)
  const int hl   = wq >> 1;            // head_local 0/1

  if (t < 64) eL[t] = 0.f;
  __syncthreads();

  floatx16 a0, a1;
#pragma unroll
  for (int r = 0; r < 16; ++r) { a0[r] = 0.f; a1[r] = 0.f; }

  const float* xrow = X + (size_t)(j0 + ml) * 256 + kh * 8;   // this lane's A row
  const float* wcol = W + (size_t)(kh * 8) * 512 + c;          // this lane's B col

#pragma unroll
  for (int kp = 0; kp < 4; ++kp) {     // kt = ks*8 + 2kp, +1
    const int kb0 = (ks * 8 + 2 * kp) * 16, kb1 = kb0 + 16;
    float xv0[8], xv1[8];
    {
      float4 u0 = *(const float4*)(xrow + kb0);
      float4 u1 = *(const float4*)(xrow + kb0 + 4);
      float4 u2 = *(const float4*)(xrow + kb1);
      float4 u3 = *(const float4*)(xrow + kb1 + 4);
      xv0[0]=u0.x; xv0[1]=u0.y; xv0[2]=u0.z; xv0[3]=u0.w;
      xv0[4]=u1.x; xv0[5]=u1.y; xv0[6]=u1.z; xv0[7]=u1.w;
      xv1[0]=u2.x; xv1[1]=u2.y; xv1[2]=u2.z; xv1[3]=u2.w;
      xv1[4]=u3.x; xv1[5]=u3.y; xv1[6]=u3.z; xv1[7]=u3.w;
    }
    float wv0[8], wv1[8];
#pragma unroll
    for (int i = 0; i < 8; ++i) {
      wv0[i] = wcol[(size_t)(kb0 + i) * 512];
      wv1[i] = wcol[(size_t)(kb1 + i) * 512];
    }
    short8 xh0, xl0, xh1, xl1, wh0, wl0, wh1, wl1;
    split8(xv0, xh0, xl0); split8(xv1, xh1, xl1);
    split8(wv0, wh0, wl0); split8(wv1, wh1, wl1);
    a0 = __builtin_amdgcn_mfma_f32_32x32x16_bf16(xh0, wh0, a0, 0, 0, 0);
    a1 = __builtin_amdgcn_mfma_f32_32x32x16_bf16(xh1, wh1, a1, 0, 0, 0);
    a0 = __builtin_amdgcn_mfma_f32_32x32x16_bf16(xh0, wl0, a0, 0, 0, 0);
    a1 = __builtin_amdgcn_mfma_f32_32x32x16_bf16(xh1, wl1, a1, 0, 0, 0);
    a0 = __builtin_amdgcn_mfma_f32_32x32x16_bf16(xl0, wh0, a0, 0, 0, 0);
    a1 = __builtin_amdgcn_mfma_f32_32x32x16_bf16(xl1, wh1, a1, 0, 0, 0);
  }
  floatx16 hacc;
#pragma unroll
  for (int r = 0; r < 16; ++r) hacc[r] = a0[r] + a1[r];

  // combine K-halves: ks=1 deposits, ks=0 adds
  if (ks == 1) {
#pragma unroll
    for (int r = 0; r < 16; ++r) hbuf[wq][lane][r] = hacc[r];
  }
  __syncthreads();
  if (ks == 0) {
#pragma unroll
    for (int r = 0; r < 16; ++r) hacc[r] += hbuf[wq][lane][r];

    const float ad = av[64 + (c & 63)];
    float p[16];
#pragma unroll
    for (int r = 0; r < 16; ++r) p[r] = hacc[r] * ad;
#pragma unroll
    for (int m = 1; m <= 16; m <<= 1)
#pragma unroll
      for (int r = 0; r < 16; ++r) p[r] += __shfl_xor(p[r], m);
    if (ml == 0) {
#pragma unroll
      for (int r = 0; r < 16; ++r) {
        int jl = (r & 3) + 8 * (r >> 2) + 4 * kh;
        atomicAdd(&eL[jl * 2 + hl], p[r]);
      }
    }
  }
  __syncthreads();
  if (t < 64) {
    float e = fminf(30.f, fmaxf(-30.f, eL[t]));
    w8L[t] = __expf(e);
  }
  __syncthreads();

  if (ks == 0) {
#pragma unroll
    for (int r = 0; r < 16; ++r) {
      int jl = (r & 3) + 8 * (r >> 2) + 4 * kh;
      int j  = j0 + jl;
      float g = hacc[r] * w8L[jl * 2 + hl];
      Gtp[(size_t)((j >> 4) * 17 + ct) * 512 + ((c & 31) + 32 * ((j & 15) >> 3)) * 8 + (j & 7)] =
          f2bf(g);
    }
  }
  if (t < 64) {
    int jj = t >> 1, lh2 = t & 1, h = 2 * y + lh2, j = j0 + jj;
    Gtp[(size_t)((j >> 4) * 17 + 16) * 512 + (h + 32 * ((jj & 15) >> 3)) * 8 + (jj & 7)] =
        f2bf(w8L[jj * 2 + lh2]);
  }
  if (y == 3 && t < 96) {
    int tk2 = t / 48, r = t - tk2 * 48;
    int slot = (r < 24) ? (8 + r) : (16 + r);
    u16x8 z = {0, 0, 0, 0, 0, 0, 0, 0};
    *(u16x8*)(Gtp + (size_t)(((j0 >> 4) + tk2) * 17 + 16) * 512 + slot * 8) = z;
  }
}

// ---------------------------------------------------------------------------
// Kernel 2: out = relu( (A x G^T)[num] / (A x G^T)[den] ), full K per block.
// Grid 512 = 128 strips x 4 n-quarters (XCD decode co-locates a strip's 4
// quarters); block = 32 rows x 4 n-tiles, 8 waves = (wq n-tile) x (ks K-half).
// 8 chunk-iters of 512 cols (A dbuf 2x32 KB, R15 staging); wave handles its
// ks-half's 16 k-tiles per chunk = 4 ds-iters x {4 B-loads + 4 A reads +
// 4 MFMA}. Den: ksub {4wq..4wq+3} of own half per chunk. End: num combine
// over ks (LDS), den reduce over 8 waves, relu(num/den) -> direct out.
// ---------------------------------------------------------------------------
__global__ __launch_bounds__(512, 4) void k_gemm(const float* __restrict__ A,
                                                 const u16* __restrict__ Gtp,
                                                 float* __restrict__ out) {
  __shared__ __align__(16) u16 As[2][32 * 512];  // 2 x 32 KB
  const int t    = threadIdx.x;
  const int bid  = blockIdx.x;
  const int xcd  = bid & 7, seq = bid >> 3;      // HW round-robins blockIdx%8 -> XCD
  const int idx  = (xcd << 6) + seq;             // 0..511; strip's 4 nq share an XCD
  const int strip = idx >> 2;                    // 0..127
  const int nq   = idx & 3;                      // n-quarter
  const int i0   = strip * 32;
  const int w    = t >> 6, lane = t & 63;
  const int ml   = lane & 31, kh = lane >> 5;
  const int wq   = w & 3;                        // n-tile slot
  const int ks   = w >> 2;                       // K-half
  const int nt   = nq * 4 + wq;                  // this wave's n-tile (0..15)

  floatx16 c0, dn;
#pragma unroll
  for (int r = 0; r < 16; ++r) { c0[r] = 0.f; dn[r] = 0.f; }

  // A staging (R15-verified): thread -> row ar (0..31), q-th float4 at
  // col = (t&15)*4 + q*64 of the 512-col chunk; unit = q*8+scb, phys ^arx.
  const int ar  = t >> 4;
  const int af  = (t & 15) * 4;
  const float* pa = A + (size_t)(i0 + ar) * 4096 + af;
  const int sbase = ar * 512 + (t & 1) * 4;
  const int scb   = (t & 15) >> 1;
  const int arx   = ar & 7;

  // A-frag reads: row ml, k-tile j of own half -> unit (ks*32 + 2j + kh) ^ mx
  const int arow = ml * 512;
  const int mx   = ml & 7;
  const int ub   = ks * 32;

  float4 areg[8];
#pragma unroll
  for (int q = 0; q < 8; ++q) areg[q] = *(const float4*)(pa + q * 64);
#pragma unroll
  for (int q = 0; q < 8; ++q) {
    u16x4 v = {f2bf(areg[q].x), f2bf(areg[q].y), f2bf(areg[q].z), f2bf(areg[q].w)};
    *(u16x4*)(&As[0][sbase + ((q * 8 + scb) ^ arx) * 8]) = v;
  }
  __syncthreads();

  for (int cc = 0; cc < 8; ++cc) {
    const int cb = cc & 1;
    if (cc < 7) {                    // prefetch next 512-col chunk
#pragma unroll
      for (int q = 0; q < 8; ++q)
        areg[q] = *(const float4*)(pa + (cc + 1) * 512 + q * 64);
    }
    const int ktb = cc * 32 + ks * 16;   // this wave's k-tile base in Gtp
#pragma unroll 2
    for (int ds = 0; ds < 4; ++ds) {
      short8 b0 = *(const short8*)(Gtp + (size_t)((ktb + ds * 4 + 0) * 17 + nt) * 512 + lane * 8);
      short8 b1 = *(const short8*)(Gtp + (size_t)((ktb + ds * 4 + 1) * 17 + nt) * 512 + lane * 8);
      short8 b2 = *(const short8*)(Gtp + (size_t)((ktb + ds * 4 + 2) * 17 + nt) * 512 + lane * 8);
      short8 b3 = *(const short8*)(Gtp + (size_t)((ktb + ds * 4 + 3) * 17 + nt) * 512 + lane * 8);
      short8 a0 = *(const short8*)(&As[cb][arow + ((ub + ds * 8 + 0 + kh) ^ mx) * 8]);
      short8 a1 = *(const short8*)(&As[cb][arow + ((ub + ds * 8 + 2 + kh) ^ mx) * 8]);
      short8 a2 = *(const short8*)(&As[cb][arow + ((ub + ds * 8 + 4 + kh) ^ mx) * 8]);
      short8 a3 = *(const short8*)(&As[cb][arow + ((ub + ds * 8 + 6 + kh) ^ mx) * 8]);
      c0 = __builtin_amdgcn_mfma_f32_32x32x16_bf16(a0, b0, c0, 0, 0, 0);
      c0 = __builtin_amdgcn_mfma_f32_32x32x16_bf16(a1, b1, c0, 0, 0, 0);
      c0 = __builtin_amdgcn_mfma_f32_32x32x16_bf16(a2, b2, c0, 0, 0, 0);
      c0 = __builtin_amdgcn_mfma_f32_32x32x16_bf16(a3, b3, c0, 0, 0, 0);
    }
    // den tile 16: wave covers k-tiles {4wq..4wq+3} of its half
#pragma unroll
    for (int q2 = 0; q2 < 4; ++q2) {
      int j = wq * 4 + q2;
      short8 e = *(const short8*)(Gtp + (size_t)((ktb + j) * 17 + 16) * 512 + lane * 8);
      short8 a = *(const short8*)(&As[cb][arow + ((ub + 2 * j + kh) ^ mx) * 8]);
      dn = __builtin_amdgcn_mfma_f32_32x32x16_bf16(a, e, dn, 0, 0, 0);
    }
    if (cc < 7) {
      __syncthreads();               // readers of other buffer done
#pragma unroll
      for (int q = 0; q < 8; ++q) {
        u16x4 v = {f2bf(areg[q].x), f2bf(areg[q].y), f2bf(areg[q].z), f2bf(areg[q].w)};
        *(u16x4*)(&As[cb ^ 1][sbase + ((q * 8 + scb) ^ arx) * 8]) = v;
      }
      __syncthreads();               // writes visible
    }
  }

  // ---- combine: num over ks, den over all 8 waves; divide; store out ----
  // As[0] free: last As[0] read was chunk cc==6; cc==7 reads As[1] only.
  float* hnum = (float*)&As[0][0];          // 4 wq x 64 lanes x 16 = 16 KB
  float* dred = hnum + 4096;                // 8 waves x 32 rows x 8 = 8 KB
  float* dsum = dred + 2048;                // 32 rows x 8 = 1 KB
  if (ks == 1) {
#pragma unroll
    for (int r = 0; r < 16; ++r) hnum[(wq * 64 + lane) * 16 + r] = c0[r];
  }
  if (ml < 8) {
#pragma unroll
    for (int r = 0; r < 16; ++r) {
      int row32 = 4 * kh + (r & 3) + 8 * (r >> 2);
      dred[(w * 32 + row32) * 8 + ml] = dn[r];
    }
  }
  __syncthreads();
  if (t < 256) {
    int row = t >> 3, hd = t & 7;    // 32 rows x 8 heads
    float s = 0.f;
#pragma unroll
    for (int ww = 0; ww < 8; ++ww) s += dred[(ww * 32 + row) * 8 + hd];
    dsum[row * 8 + hd] = s;
  }
  __syncthreads();

  if (ks == 0) {
    const int hd   = nt >> 1;
    const int ucol = ((nt & 1) * 32 + ml) * 8 + hd;
#pragma unroll
    for (int r = 0; r < 16; ++r) {
      int row32 = 4 * kh + (r & 3) + 8 * (r >> 2);
      float num = c0[r] + hnum[(wq * 64 + lane) * 16 + r];
      float den = dsum[row32 * 8 + hd];
      out[(size_t)(i0 + row32) * 512 + ucol] = fmaxf(num / den, 0.f);
    }
  }
}

extern "C" void kernel_launch(void* const* d_in, const int* in_sizes, int n_in,
                              void* d_out, int out_size, void* d_ws, size_t ws_size,
                              hipStream_t stream) {
  const float* X  = (const float*)d_in[0];
  const float* A  = (const float*)d_in[1];
  const float* W  = (const float*)d_in[2];
  const float* av = (const float*)d_in[3];
  float* out = (float*)d_out;
  char*  ws  = (char*)d_ws;

  u16* Gtp = (u16*)ws;                      // 256*17 tiles * 1024 B

  k_hg<<<dim3(128, 4), 512, 0, stream>>>(X, W, av, Gtp);
  k_gemm<<<512, 512, 0, stream>>>(A, Gtp, out);
}

// Round 18
// 144.164 us; speedup vs baseline: 1.2963x; 1.2054x over previous
//
#include <hip/hip_runtime.h>

// GraphAttentionLayer: B=1, N=4096, F=256, H=8, U=64
//
// e_src cancels in softmax over j =>
//   out[i, u*8+h] = relu( (A @ (w*h))[i, h*64+u] / (A @ w)[i, h] ),  w = exp(e_dst)
// => ONE dense GEMM  C = A(4096x4096) x G(4096x544), G = [w*h (512) | w (8) | 0 (24)]
//
// R20: combine the two k_hg wins never tried together (R19's fusion arc is
// closed: full-K BM=32 quadrupled A traffic, 78us k_gemm):
//  - R11-proven k_pre: X,W -> hi/lo bf16 MFMA-frag tiles (conversion ONCE,
//    amortized; k_hg K-loop becomes pure {4 indep 16B L2-hot loads + 3 MFMA}
//    per kt — no split8 VALU (~2300 inst/wave), 80->32 load inst/wave).
//  - R14-proven 8-wave k_hg: (wq n-tile) x (ks K-half) = 4 waves/SIMD.
//  k_gemm: R14's exact 44.0us version (4-deep; reverts R16's 8-deep 46us).
//  k_out: R15 float4.
//
// Gtp layout (HW-verified R4): tile (tk=k>>4, nt=n>>5), id=tk*17+nt, 1024 B:
//   u16[ id*512 + ((n&31) + 32*((k&15)>>3))*8 + (k&7) ]
// A/B MFMA frag (HW-verified R11): data[lane*8+i] = M[row=lane&31][k=(lane>>5)*8+i]
//
// ws: P 2 slabs (17,039,360 B; Xp-hi/lo alias first 4 MB, dead before k_gemm
//     writes P) | Gtp @17039360 (4,456,448 B) | Wph @21495808 (262,144 B) |
//     Wpl @21757952 (262,144 B). Total 22,020,096 B.

typedef unsigned short u16;
typedef unsigned int   u32;
typedef __attribute__((ext_vector_type(8)))  short  short8;    // 8 bf16 (4 VGPR)
typedef __attribute__((ext_vector_type(16))) float  floatx16;  // 32x32 MFMA acc
typedef __attribute__((ext_vector_type(8)))  unsigned short u16x8;
typedef __attribute__((ext_vector_type(4)))  unsigned short u16x4;

__device__ __forceinline__ u16 f2bf(float x) {
  u32 u = __float_as_uint(x);
  u += 0x7fffu + ((u >> 16) & 1u);   // RNE
  return (u16)(u >> 16);
}
__device__ __forceinline__ float bf2f(u16 h) {
  return __uint_as_float((u32)h << 16);
}

// ---------------------------------------------------------------------------
// Kernel 0: X,W fp32 -> hi/lo bf16 in MFMA-frag tile layout (R11-verified).
//  Xp: tile (mt 0..127, kt 0..15) id = mt*16+kt, data[lane*8+i] =
//      X[mt*32+(lane&31)][kt*16+(lane>>5)*8+i]
//  Wp: tile (ct 0..15, kt 0..15) id = ct*16+kt, data[lane*8+i] =
//      W[kt*16+(lane>>5)*8+i][ct*32+(lane&31)]
// Grid 576 x 256: b<512 -> X (2048 tiles x 64), else W (256 x 64).
// ---------------------------------------------------------------------------
__global__ __launch_bounds__(256) void k_pre(const float* __restrict__ X,
                                             const float* __restrict__ W,
                                             u16* __restrict__ Xph, u16* __restrict__ Xpl,
                                             u16* __restrict__ Wph, u16* __restrict__ Wpl) {
  const int b = blockIdx.x, t = threadIdx.x;
  float xv[8];
  u16* dh; u16* dl; size_t doff;
  if (b < 512) {
    int tid  = b * 256 + t;
    int tile = tid >> 6, lane = tid & 63;
    int j = (tile >> 4) * 32 + (lane & 31);
    int k = (tile & 15) * 16 + (lane >> 5) * 8;
    const float* xp = X + (size_t)j * 256 + k;
    float4 v0 = *(const float4*)xp;
    float4 v1 = *(const float4*)(xp + 4);
    xv[0]=v0.x; xv[1]=v0.y; xv[2]=v0.z; xv[3]=v0.w;
    xv[4]=v1.x; xv[5]=v1.y; xv[6]=v1.z; xv[7]=v1.w;
    dh = Xph; dl = Xpl; doff = (size_t)tile * 512 + lane * 8;
  } else {
    int tid  = (b - 512) * 256 + t;
    int tile = tid >> 6, lane = tid & 63;
    int c = (tile >> 4) * 32 + (lane & 31);
    int k = (tile & 15) * 16 + (lane >> 5) * 8;
#pragma unroll
    for (int i = 0; i < 8; ++i) xv[i] = W[(size_t)(k + i) * 512 + c];
    dh = Wph; dl = Wpl; doff = (size_t)tile * 512 + lane * 8;
  }
  u16x8 hi, lo;
#pragma unroll
  for (int i = 0; i < 8; ++i) {
    u16 h = f2bf(xv[i]);
    hi[i] = h;
    lo[i] = f2bf(xv[i] - bf2f(h));
  }
  *(u16x8*)(dh + doff) = hi;
  *(u16x8*)(dl + doff) = lo;
}

// ---------------------------------------------------------------------------
// Kernel 1: h = X@W via split-bf16 3-pass MFMA from pre-tiled fragments.
// 512 thr = 8 waves = (wq: n-tile ct = y*4+wq) x (ks: K-half, 8 kt each).
// Per kt: 4 indep 16B L2-hot loads + 3 MFMA — NO conversion VALU, no LDS
// staging in K loop. ks=1 partials -> hbuf; ks=0 combines; e-butterfly + eL
// atomics; exp; ks=0 scatters scaled bf16 to Gtp. Grid (128,4) = 512 blocks.
// ---------------------------------------------------------------------------
__global__ __launch_bounds__(512, 4) void k_hg(const u16* __restrict__ Xph,
                                               const u16* __restrict__ Xpl,
                                               const u16* __restrict__ Wph,
                                               const u16* __restrict__ Wpl,
                                               const float* __restrict__ av,
                                               u16* __restrict__ Gtp) {
  __shared__ float hbuf[4][64][17];   // partial-h exchange, pad 17 (17.4 KB)
  __shared__ float eL[64];            // [j_local*2 + head_local]
  __shared__ float w8L[64];
  const int t    = threadIdx.x;
  const int bx   = blockIdx.x;         // m-tile (32 j)
  const int y    = blockIdx.y;         // heads 2y, 2y+1
  const int j0   = bx * 32;
  const int wn   = t >> 6, lane = t & 63;
  const int ml   = lane & 31, kh = lane >> 5;
  const int wq   = wn & 3;             // n-tile slot
  const int ks   = wn >> 2;            // K-half
  const int ct   = y * 4 + wq;
  const int c    = ct * 32 + ml;       // global col (0..511)
  const int hl   = wq >> 1;            // head_local 0/1

  if (t < 64) eL[t] = 0.f;
  __syncthreads();

  floatx16 a0, a1;
#pragma unroll
  for (int r = 0; r < 16; ++r) { a0[r] = 0.f; a1[r] = 0.f; }

  const u16* xh = Xph + (size_t)(bx * 16 + ks * 8) * 512 + lane * 8;
  const u16* xl = Xpl + (size_t)(bx * 16 + ks * 8) * 512 + lane * 8;
  const u16* wh = Wph + (size_t)(ct * 16 + ks * 8) * 512 + lane * 8;
  const u16* wl = Wpl + (size_t)(ct * 16 + ks * 8) * 512 + lane * 8;

#pragma unroll
  for (int kp = 0; kp < 4; ++kp) {     // local kt = 2kp, 2kp+1
    short8 fxh0 = *(const short8*)(xh + (size_t)(2 * kp) * 512);
    short8 fxl0 = *(const short8*)(xl + (size_t)(2 * kp) * 512);
    short8 fwh0 = *(const short8*)(wh + (size_t)(2 * kp) * 512);
    short8 fwl0 = *(const short8*)(wl + (size_t)(2 * kp) * 512);
    short8 fxh1 = *(const short8*)(xh + (size_t)(2 * kp + 1) * 512);
    short8 fxl1 = *(const short8*)(xl + (size_t)(2 * kp + 1) * 512);
    short8 fwh1 = *(const short8*)(wh + (size_t)(2 * kp + 1) * 512);
    short8 fwl1 = *(const short8*)(wl + (size_t)(2 * kp + 1) * 512);
    a0 = __builtin_amdgcn_mfma_f32_32x32x16_bf16(fxh0, fwh0, a0, 0, 0, 0);
    a1 = __builtin_amdgcn_mfma_f32_32x32x16_bf16(fxh1, fwh1, a1, 0, 0, 0);
    a0 = __builtin_amdgcn_mfma_f32_32x32x16_bf16(fxh0, fwl0, a0, 0, 0, 0);
    a1 = __builtin_amdgcn_mfma_f32_32x32x16_bf16(fxh1, fwl1, a1, 0, 0, 0);
    a0 = __builtin_amdgcn_mfma_f32_32x32x16_bf16(fxl0, fwh0, a0, 0, 0, 0);
    a1 = __builtin_amdgcn_mfma_f32_32x32x16_bf16(fxl1, fwh1, a1, 0, 0, 0);
  }
  floatx16 hacc;
#pragma unroll
  for (int r = 0; r < 16; ++r) hacc[r] = a0[r] + a1[r];

  // combine K-halves: ks=1 deposits, ks=0 adds (R14-verified)
  if (ks == 1) {
#pragma unroll
    for (int r = 0; r < 16; ++r) hbuf[wq][lane][r] = hacc[r];
  }
  __syncthreads();
  if (ks == 0) {
#pragma unroll
    for (int r = 0; r < 16; ++r) hacc[r] += hbuf[wq][lane][r];

    const float ad = av[64 + (c & 63)];
    float p[16];
#pragma unroll
    for (int r = 0; r < 16; ++r) p[r] = hacc[r] * ad;
#pragma unroll
    for (int m = 1; m <= 16; m <<= 1)
#pragma unroll
      for (int r = 0; r < 16; ++r) p[r] += __shfl_xor(p[r], m);
    if (ml == 0) {
#pragma unroll
      for (int r = 0; r < 16; ++r) {
        int jl = (r & 3) + 8 * (r >> 2) + 4 * kh;
        atomicAdd(&eL[jl * 2 + hl], p[r]);
      }
    }
  }
  __syncthreads();
  if (t < 64) {
    float e = fminf(30.f, fmaxf(-30.f, eL[t]));
    w8L[t] = __expf(e);
  }
  __syncthreads();

  if (ks == 0) {
#pragma unroll
    for (int r = 0; r < 16; ++r) {
      int jl = (r & 3) + 8 * (r >> 2) + 4 * kh;
      int j  = j0 + jl;
      float g = hacc[r] * w8L[jl * 2 + hl];
      Gtp[(size_t)((j >> 4) * 17 + ct) * 512 + ((c & 31) + 32 * ((j & 15) >> 3)) * 8 + (j & 7)] =
          f2bf(g);
    }
  }
  if (t < 64) {
    int jj = t >> 1, lh2 = t & 1, h = 2 * y + lh2, j = j0 + jj;
    Gtp[(size_t)((j >> 4) * 17 + 16) * 512 + (h + 32 * ((jj & 15) >> 3)) * 8 + (jj & 7)] =
        f2bf(w8L[jj * 2 + lh2]);
  }
  if (y == 3 && t < 96) {
    int tk2 = t / 48, r = t - tk2 * 48;
    int slot = (r < 24) ? (8 + r) : (16 + r);
    u16x8 z = {0, 0, 0, 0, 0, 0, 0, 0};
    *(u16x8*)(Gtp + (size_t)(((j0 >> 4) + tk2) * 17 + 16) * 512 + slot * 8) = z;
  }
}

// ---------------------------------------------------------------------------
// Kernel 2: Pz = A(fp32,{0,1}) x G^T via 32x32x16 bf16 MFMA, PLAIN stores.
// (R14's exact 44.0us version: BM=32, N-split, wave owns 1 n-tile, 4 indep
// B-loads + 4 A ds_reads + 4 MFMA per ds-iter, Z=2, XCD-pinned.)
// ---------------------------------------------------------------------------
__global__ __launch_bounds__(512, 4) void k_gemm(const float* __restrict__ A,
                                                 const u16* __restrict__ Gtp,
                                                 float* __restrict__ P) {
  __shared__ __align__(16) u16 As[2][32 * 256];  // 2 x 16 KB
  const int t    = threadIdx.x;
  const int bid  = blockIdx.x;
  const int xcd  = bid & 7, seq = bid >> 3;      // HW round-robins blockIdx%8 -> XCD
  const int z    = xcd >> 2;                     // k-slice, constant per XCD
  const int idx  = ((xcd & 3) << 6) + seq;       // 0..255 per z
  const int strip = idx >> 1;                    // 0..127
  const int nh   = idx & 1;                      // n-half
  const int i0   = strip * 32;
  const int kt0  = z * 2048;
  const int w    = t >> 6, lane = t & 63;
  const int ml   = lane & 31, kh = lane >> 5;
  const int nt   = nh * 8 + w;                   // this wave's n-tile

  floatx16 c0, dn;
#pragma unroll
  for (int r = 0; r < 16; ++r) { c0[r] = 0.f; dn[r] = 0.f; }

  // A staging: thread -> row ar (0..31), q-th float4 at k = (t&15)*4 + q*64
  const int ar  = t >> 4;
  const int af  = (t & 15) * 4;
  const float* pa = A + (size_t)(i0 + ar) * 4096 + kt0 + af;
  const int sbase = ar * 256 + (t & 1) * 4;   // + swizzled granule*8
  const int scb   = (t & 15) >> 1;            // granule = q*8 + scb
  const int arx   = ar & 7;

  // A-frag reads: row m = ml, granule g -> physical g^(ml&7); k-tile j <-> granule 2j+kh
  const int arow = ml * 256;
  const int mx   = ml & 7;

  float4 areg[4];
#pragma unroll
  for (int q = 0; q < 4; ++q) areg[q] = *(const float4*)(pa + q * 64);
#pragma unroll
  for (int q = 0; q < 4; ++q) {
    u16x4 v = {f2bf(areg[q].x), f2bf(areg[q].y), f2bf(areg[q].z), f2bf(areg[q].w)};
    *(u16x4*)(&As[0][sbase + ((q * 8 + scb) ^ arx) * 8]) = v;
  }
  __syncthreads();

  for (int cc = 0; cc < 8; ++cc) {
    const int cb = cc & 1;
    if (cc < 7) {                    // prefetch next chunk early (hidden by compute)
#pragma unroll
      for (int q = 0; q < 4; ++q)
        areg[q] = *(const float4*)(pa + (cc + 1) * 256 + q * 64);
    }
    const int ktb = (kt0 >> 4) + cc * 16;
#pragma unroll 2
    for (int ds = 0; ds < 4; ++ds) {
      short8 b0 = *(const short8*)(Gtp + (size_t)((ktb + ds * 4 + 0) * 17 + nt) * 512 + lane * 8);
      short8 b1 = *(const short8*)(Gtp + (size_t)((ktb + ds * 4 + 1) * 17 + nt) * 512 + lane * 8);
      short8 b2 = *(const short8*)(Gtp + (size_t)((ktb + ds * 4 + 2) * 17 + nt) * 512 + lane * 8);
      short8 b3 = *(const short8*)(Gtp + (size_t)((ktb + ds * 4 + 3) * 17 + nt) * 512 + lane * 8);
      short8 a0 = *(const short8*)(&As[cb][arow + ((ds * 8 + 0 + kh) ^ mx) * 8]);
      short8 a1 = *(const short8*)(&As[cb][arow + ((ds * 8 + 2 + kh) ^ mx) * 8]);
      short8 a2 = *(const short8*)(&As[cb][arow + ((ds * 8 + 4 + kh) ^ mx) * 8]);
      short8 a3 = *(const short8*)(&As[cb][arow + ((ds * 8 + 6 + kh) ^ mx) * 8]);
      c0 = __builtin_amdgcn_mfma_f32_32x32x16_bf16(a0, b0, c0, 0, 0, 0);
      c0 = __builtin_amdgcn_mfma_f32_32x32x16_bf16(a1, b1, c0, 0, 0, 0);
      c0 = __builtin_amdgcn_mfma_f32_32x32x16_bf16(a2, b2, c0, 0, 0, 0);
      c0 = __builtin_amdgcn_mfma_f32_32x32x16_bf16(a3, b3, c0, 0, 0, 0);
    }
    // den tile 16: wave covers k-tiles {2w, 2w+1} of this chunk (nh==0 only)
    if (nh == 0) {
      short8 e0 = *(const short8*)(Gtp + (size_t)((ktb + w * 2) * 17 + 16) * 512 + lane * 8);
      short8 e1 = *(const short8*)(Gtp + (size_t)((ktb + w * 2 + 1) * 17 + 16) * 512 + lane * 8);
      short8 a0 = *(const short8*)(&As[cb][arow + ((w * 4 + kh) ^ mx) * 8]);
      short8 a1 = *(const short8*)(&As[cb][arow + ((w * 4 + 2 + kh) ^ mx) * 8]);
      dn = __builtin_amdgcn_mfma_f32_32x32x16_bf16(a0, e0, dn, 0, 0, 0);
      dn = __builtin_amdgcn_mfma_f32_32x32x16_bf16(a1, e1, dn, 0, 0, 0);
    }
    if (cc < 7) {
      __syncthreads();               // readers of other buffer done
#pragma unroll
      for (int q = 0; q < 4; ++q) {
        u16x4 v = {f2bf(areg[q].x), f2bf(areg[q].y), f2bf(areg[q].z), f2bf(areg[q].w)};
        *(u16x4*)(&As[cb ^ 1][sbase + ((q * 8 + scb) ^ arx) * 8]) = v;
      }
      __syncthreads();               // writes visible
    }
  }

  // ---- epilogue: plain stores to slab z (no atomics) ----
  float* Pz = P + (size_t)z * (4096 * 520);
  const int col0 = nt * 32 + ml;
  // C/D layout: col = lane&31, row = (r&3) + 8*(r>>2) + 4*(lane>>5)
#pragma unroll
  for (int r = 0; r < 16; ++r) {
    int row = i0 + 4 * kh + (r & 3) + 8 * (r >> 2);
    Pz[(size_t)row * 520 + col0] = c0[r];
  }

  // den cols 512..519: reduce dn across the 8 waves via LDS (As[0] free:
  // last read in chunk cc==6, all waves past that barrier).
  if (nh == 0) {
    float* dred = (float*)&As[0][0];   // 8 waves x 32 rows x 8 cols = 8 KB
    if (ml < 8) {
#pragma unroll
      for (int r = 0; r < 16; ++r) {
        int row32 = 4 * kh + (r & 3) + 8 * (r >> 2);
        dred[(w * 32 + row32) * 8 + ml] = dn[r];
      }
    }
    __syncthreads();
    if (t < 256) {
      int row = t >> 3, c = t & 7;   // 32 rows x 8 cols
      float s = 0.f;
#pragma unroll
      for (int ww = 0; ww < 8; ++ww) s += dred[(ww * 32 + row) * 8 + c];
      Pz[(size_t)(i0 + row) * 520 + 512 + c] = s;
    }
  }
}

// ---------------------------------------------------------------------------
// Kernel 3: out[i, u*8+h] = relu( SUMz Pz[i][h*64+u] / SUMz Pz[i][512+h] ).
// float4 loads/stores. 2 rows/block, 2048 blocks.
// ---------------------------------------------------------------------------
__global__ __launch_bounds__(256) void k_out(const float* __restrict__ P,
                                             float* __restrict__ out) {
  __shared__ float ps[2][520];
  const size_t SL = (size_t)4096 * 520;
  const int t    = threadIdx.x;
  const int half = t >> 7, lt = t & 127;
  const int i    = blockIdx.x * 2 + half;
  const float* pr = P + (size_t)i * 520;
  {
    float4 v0 = *(const float4*)(pr + lt * 4);
    float4 v1 = *(const float4*)(pr + SL + lt * 4);
    float4 s  = {v0.x + v1.x, v0.y + v1.y, v0.z + v1.z, v0.w + v1.w};
    *(float4*)(&ps[half][lt * 4]) = s;
    if (lt < 8) ps[half][512 + lt] = pr[512 + lt] + pr[SL + 512 + lt];
  }
  __syncthreads();
  {
    float ov[4];
#pragma unroll
    for (int q = 0; q < 4; ++q) {
      int c = lt * 4 + q;             // c = u*8 + hd
      int u = c >> 3, hd = c & 7;
      float o = ps[half][hd * 64 + u] / ps[half][512 + hd];
      ov[q] = fmaxf(o, 0.f);
    }
    *(float4*)(out + (size_t)i * 512 + lt * 4) = *(float4*)ov;
  }
}

extern "C" void kernel_launch(void* const* d_in, const int* in_sizes, int n_in,
                              void* d_out, int out_size, void* d_ws, size_t ws_size,
                              hipStream_t stream) {
  const float* X  = (const float*)d_in[0];
  const float* A  = (const float*)d_in[1];
  const float* W  = (const float*)d_in[2];
  const float* av = (const float*)d_in[3];
  float* out = (float*)d_out;
  char*  ws  = (char*)d_ws;

  float* P   = (float*)ws;                  // 2 slabs x 4096 x 520 fp32
  u16*   Xph = (u16*)ws;                    // aliases P[0:2MB)  (dead before k_gemm)
  u16*   Xpl = (u16*)(ws + 2097152);        // aliases P[2MB:4MB)
  u16*   Gtp = (u16*)(ws + 17039360);       // 256*17 tiles * 1024 B
  u16*   Wph = (u16*)(ws + 21495808);       // 256 tiles * 1024 B
  u16*   Wpl = (u16*)(ws + 21757952);       // 256 tiles * 1024 B

  k_pre<<<576, 256, 0, stream>>>(X, W, Xph, Xpl, Wph, Wpl);
  k_hg<<<dim3(128, 4), 512, 0, stream>>>(Xph, Xpl, Wph, Wpl, av, Gtp);
  k_gemm<<<512, 512, 0, stream>>>(A, Gtp, P);
  k_out<<<2048, 256, 0, stream>>>(P, out);
}